// Round 7
// baseline (155.351 us; speedup 1.0000x reference)
//
#include <hip/hip_runtime.h>

#define B_     128
#define S_     256
#define MW_    21
#define VOCAB_ 100
#define EC_    50
#define EW_    256
#define KW_    5
#define T_     17              // MW - K + 1
#define NW_    (B_ * S_)       // 32768 words
#define GROWS  (VOCAB_ * KW_)  // 500
#define WPB    64              // words per mega block (R7: halved for role-split)
#define P1B    200             // prep part-1 blocks: 50 v-pairs x 4 o-tiles

typedef _Float16 f16x8 __attribute__((ext_vector_type(8)));
typedef float    f32x4 __attribute__((ext_vector_type(4)));

// ---------------- kernel 1: prep (unchanged from R1)
__global__ __launch_bounds__(256) void k_prep(const float* __restrict__ emb,
                                              const float* __restrict__ cw,
                                              const float* __restrict__ Wp,
                                              const float* __restrict__ Wg,
                                              _Float16* __restrict__ g,
                                              _Float16* __restrict__ wpf,
                                              _Float16* __restrict__ wgf) {
  const int bi = blockIdx.x;
  if (bi < P1B) {
    __shared__ float ls[64 * 250];          // one o-tile of cw, natural layout
    const int vp = bi >> 2, ot = bi & 3;
    const int o0 = ot * 64;
    const int tid = threadIdx.x;
    const float4* __restrict__ cw4 = (const float4*)cw + ot * 4000;  // tile base
#pragma unroll 4
    for (int idx4 = tid; idx4 < 4000; idx4 += 256)
      *(float4*)&ls[idx4 * 4] = cw4[idx4];
    __syncthreads();

    const int l = tid & 63, wv = tid >> 6;   // lane = o_local, wave = k (0..3)
#pragma unroll
    for (int vv = 0; vv < 2; ++vv) {
      const int v = vp * 2 + vv;
      const float* __restrict__ er = emb + v * EC_;   // uniform -> s_load
      float acc = 0.f;
#pragma unroll
      for (int i = 0; i < EC_; ++i)
        acc += er[i] * ls[l * 250 + i * KW_ + wv];
      g[(v * KW_ + wv) * EW_ + o0 + l] = (_Float16)acc;
      if (wv == 0) {                          // wave 0 also covers k = 4
        float a4 = 0.f;
#pragma unroll
        for (int i = 0; i < EC_; ++i)
          a4 += er[i] * ls[l * 250 + i * KW_ + 4];
        g[(v * KW_ + 4) * EW_ + o0 + l] = (_Float16)a4;
      }
    }
  } else {
    const int fl  = (bi - P1B) * 256 + threadIdx.x;  // 0..8191 lane-frags
    const int nt  = fl >> 9;
    const int rem = fl & 511;
    const int ks  = rem >> 6;
    const int l   = rem & 63;
    const int n   = nt * 16 + (l & 15);
    const int kc  = ks * 32 + (l >> 4) * 8;
    const int src = n * EW_ + kc;
    const float4 p0 = *(const float4*)&Wp[src], p1 = *(const float4*)&Wp[src + 4];
    const float4 q0 = *(const float4*)&Wg[src], q1 = *(const float4*)&Wg[src + 4];
    f16x8 hp = {(_Float16)p0.x, (_Float16)p0.y, (_Float16)p0.z, (_Float16)p0.w,
                (_Float16)p1.x, (_Float16)p1.y, (_Float16)p1.z, (_Float16)p1.w};
    f16x8 hg = {(_Float16)q0.x, (_Float16)q0.y, (_Float16)q0.z, (_Float16)q0.w,
                (_Float16)q1.x, (_Float16)q1.y, (_Float16)q1.z, (_Float16)q1.w};
    *(f16x8*)&wpf[fl * 8] = hp;
    *(f16x8*)&wgf[fl * 8] = hg;
  }
}

// ---------------- kernel 2: mega — R7: WAVE-ROLE SPLIT (producer/consumer)
// Evidence: phase B (~12us wall, ~4us MFMA) is latency-bound (R6: halving its
//   L2 traffic was neutral) and fully serialized after the port-bound phase A
//   (~34us, at the ds_read_b128 issue floor). Intra-wave interleave failed (R5,
//   barrier lockstep). Fix per m114 (MFMA-wave + LDS-wave co-schedule): waves
//   0-3 run the conv (identical code, 2 its), waves 4-7 run the dual GEMM on
//   the K-slices produced one chunk earlier — their MFMA + B-loads hide under
//   the conv waves' gather. WPB=64 so each GEMM wave owns 4mt x 4nt x 2 gemms
//   (128 acc VGPRs; WPB=128 would need 256 -> spill). ks stays ascending 0..7
//   -> bitwise-identical numerics. Tail: ks 6,7 + epilogue.
// LDS: y_s 32768 B ([4mt][8ks][64][8]) + g_s 64000 B = 96768 B, 1 block/CU.
// g_s: plain stride-64 (R3: padding doubled conflicts). Grid 512 blocks.
__global__ __launch_bounds__(512, 2) void k_mega(const int* __restrict__ idx,
                                                 const _Float16* __restrict__ g,
                                                 const float* __restrict__ cb,
                                                 const _Float16* __restrict__ wpf,
                                                 const _Float16* __restrict__ wgf,
                                                 const float* __restrict__ bp,
                                                 const float* __restrict__ bg,
                                                 float* __restrict__ out) {
  __shared__ __align__(16) _Float16 lds[16384 + GROWS * 64];
  _Float16* y_s = lds;            // 16384 halves: (frag*64 + (lane_t^og)) * 8 + j
  _Float16* g_s = lds + 16384;    // [500][64]

  const int tid  = threadIdx.x;
  const int wave = tid >> 6, lane = tid & 63;
  const int m0 = blockIdx.x * WPB;
  const int wq = lane >> 3, og = lane & 7;   // conv: 8 words x 8 octets per wave

  // initial stage: chunk 0 (all waves)
#pragma unroll
  for (int i = 0; i < 8; ++i) {
    const int c = tid + i * 512;
    if (c < GROWS * 8) {
      const int row = c >> 3, cc = c & 7;
      *(f16x8*)&g_s[row * 64 + cc * 8] = *(const f16x8*)&g[row * EW_ + cc * 8];
    }
  }
  __syncthreads();

  const bool isConv = wave < 4;
  const int quad = lane >> 4, r16 = lane & 15;
  const int nq = wave & 3;                   // gemm wave's n-quarter

  // conv: hoist per-it bases across chunks (chunk-invariant)
  int base[2][MW_];
  if (isConv) {
#pragma unroll
    for (int it = 0; it < 2; ++it) {
      const int wl = it * 32 + wave * 8 + wq;
      const int* __restrict__ ip = idx + (m0 + wl) * MW_;
#pragma unroll
      for (int c = 0; c < MW_; ++c)
        base[it][c] = ip[c] * (KW_ * 64) + og * 8;
    }
  }

  f32x4 accp[4][4], accg[4][4];
  if (!isConv) {
    const f32x4 zero = {0.f, 0.f, 0.f, 0.f};
#pragma unroll
    for (int mi = 0; mi < 4; ++mi)
#pragma unroll
      for (int nf = 0; nf < 4; ++nf) { accp[mi][nf] = zero; accg[mi][nf] = zero; }
  }

  f16x8 pre[8];
#pragma unroll
  for (int chunk = 0; chunk < 4; ++chunk) {
    const int oc0 = chunk * 64;
    // all waves: issue next chunk's staging loads into registers
    if (chunk < 3) {
#pragma unroll
      for (int i = 0; i < 8; ++i) {
        const int c = tid + i * 512;
        if (c < GROWS * 8) {
          const int row = c >> 3, cc = c & 7;
          pre[i] = *(const f16x8*)&g[row * EW_ + oc0 + 64 + cc * 8];
        }
      }
    }

    if (isConv) {
      // ---------------- producer: conv+relu+maxpool for this chunk
      f16x8 bias;
#pragma unroll
      for (int j = 0; j < 8; ++j) bias[j] = (_Float16)cb[oc0 + og * 8 + j];
      const int ks_w    = chunk * 2 + (og >> 2);
      const int lane_hi = (og & 3) << 4;
#pragma unroll
      for (int it = 0; it < 2; ++it) {
        const int wl = it * 32 + wave * 8 + wq;
        const _Float16 NEG = (_Float16)(-60000.0f);
        f16x8 mx = {NEG, NEG, NEG, NEG, NEG, NEG, NEG, NEG};
#pragma unroll
        for (int t = 0; t < T_; ++t) {
          f16x8 s = *(const f16x8*)&g_s[base[it][t]];              // k = 0
#pragma unroll
          for (int k = 1; k < KW_; ++k)
            s += *(const f16x8*)&g_s[base[it][t + k] + k * 64];    // v_pk_add_f16
          mx = __builtin_elementwise_max(mx, s);                   // v_pk_max_f16
        }
        const f16x8 zero8 = {0, 0, 0, 0, 0, 0, 0, 0};
        mx = __builtin_elementwise_max(mx + bias, zero8);
        const int mt = wl >> 4;
        const int lt = ((wl & 15) | lane_hi) ^ og;                 // swizzled granule
        *(f16x8*)&y_s[((mt * 8 + ks_w) * 64 + lt) * 8] = mx;
      }
    } else if (chunk > 0) {
      // ---------------- consumer: dual GEMM on chunk-1's two K-slices
#pragma unroll
      for (int ks2 = 0; ks2 < 2; ++ks2) {
        const int ks = (chunk - 1) * 2 + ks2;
        const int key = ((ks & 1) << 2) | quad;                    // == writer og
        f16x8 a[4];
#pragma unroll
        for (int mi = 0; mi < 4; ++mi)
          a[mi] = *(const f16x8*)&y_s[((mi * 8 + ks) * 64 + (lane ^ key)) * 8];
#pragma unroll
        for (int nf = 0; nf < 4; ++nf) {
          const int nt = nq * 4 + nf;
          const int off = ((nt * 8 + ks) * 64 + lane) * 8;
          const f16x8 bpv = *(const f16x8*)&wpf[off];
          const f16x8 bgv = *(const f16x8*)&wgf[off];
#pragma unroll
          for (int mi = 0; mi < 4; ++mi) {
            accp[mi][nf] = __builtin_amdgcn_mfma_f32_16x16x32_f16(a[mi], bpv, accp[mi][nf], 0, 0, 0);
            accg[mi][nf] = __builtin_amdgcn_mfma_f32_16x16x32_f16(a[mi], bgv, accg[mi][nf], 0, 0, 0);
          }
        }
      }
    }
    __syncthreads();  // conv done with g_s(c) + y(c) written; gemm done with y(c-1)
    if (chunk < 3) {
#pragma unroll
      for (int i = 0; i < 8; ++i) {
        const int c = tid + i * 512;
        if (c < GROWS * 8) {
          const int row = c >> 3, cc = c & 7;
          *(f16x8*)&g_s[row * 64 + cc * 8] = pre[i];
        }
      }
      __syncthreads();
    }
  }

  // ======== tail: gemm waves finish ks 6,7 and run the highway epilogue ========
  if (!isConv) {
#pragma unroll
    for (int ks2 = 0; ks2 < 2; ++ks2) {
      const int ks = 6 + ks2;
      const int key = ((ks & 1) << 2) | quad;
      f16x8 a[4];
#pragma unroll
      for (int mi = 0; mi < 4; ++mi)
        a[mi] = *(const f16x8*)&y_s[((mi * 8 + ks) * 64 + (lane ^ key)) * 8];
#pragma unroll
      for (int nf = 0; nf < 4; ++nf) {
        const int nt = nq * 4 + nf;
        const int off = ((nt * 8 + ks) * 64 + lane) * 8;
        const f16x8 bpv = *(const f16x8*)&wpf[off];
        const f16x8 bgv = *(const f16x8*)&wgf[off];
#pragma unroll
        for (int mi = 0; mi < 4; ++mi) {
          accp[mi][nf] = __builtin_amdgcn_mfma_f32_16x16x32_f16(a[mi], bpv, accp[mi][nf], 0, 0, 0);
          accg[mi][nf] = __builtin_amdgcn_mfma_f32_16x16x32_f16(a[mi], bgv, accg[mi][nf], 0, 0, 0);
        }
      }
    }

#pragma unroll
    for (int mi = 0; mi < 4; ++mi) {
#pragma unroll
      for (int nf = 0; nf < 4; ++nf) {
        const int n = nq * 64 + nf * 16 + r16;
        const float bpn = bp[n];
        const float bgn = bg[n];
        const int ks_e = n >> 5;
        const int lane_e = ((n >> 3) & 3) << 4;
        const int og_e = (n >> 3) & 7;
        const int je = n & 7;
#pragma unroll
        for (int reg = 0; reg < 4; ++reg) {
          const int m = mi * 16 + quad * 4 + reg;
          float p = fmaxf(accp[mi][nf][reg] + bpn, 0.f);
          const float gz = accg[mi][nf][reg] + bgn;
          const float gate = 1.f / (1.f + __expf(-gz));
          const float yv =
              (float)y_s[((mi * 8 + ks_e) * 64 + (((m & 15) | lane_e) ^ og_e)) * 8 + je];
          out[(m0 + m) * EW_ + n] = gate * p + (1.f - gate) * yv;
        }
      }
    }
  }
}

extern "C" void kernel_launch(void* const* d_in, const int* in_sizes, int n_in,
                              void* d_out, int out_size, void* d_ws, size_t ws_size,
                              hipStream_t stream) {
  (void)in_sizes; (void)n_in; (void)out_size; (void)ws_size;
  const int*   idx = (const int*)d_in[0];
  const float* emb = (const float*)d_in[1];
  const float* cw  = (const float*)d_in[2];
  const float* cb  = (const float*)d_in[3];
  const float* wp  = (const float*)d_in[4];
  const float* bpp = (const float*)d_in[5];
  const float* wgt = (const float*)d_in[6];
  const float* bgg = (const float*)d_in[7];
  float* out = (float*)d_out;
  _Float16* g_ws = (_Float16*)d_ws;            // 500*256 fp16
  _Float16* wp_f = g_ws + GROWS * EW_;         // 65536 halves, frag order
  _Float16* wg_f = wp_f + EW_ * EW_;           // 65536 halves, frag order

  k_prep<<<P1B + 32, 256, 0, stream>>>(emb, cw, wp, wgt, g_ws, wp_f, wg_f);
  k_mega<<<NW_ / WPB, 512, 0, stream>>>(idx, g_ws, cb, wp_f, wg_f, bpp, bgg, out);
}

// Round 8
// 121.106 us; speedup vs baseline: 1.2828x; 1.2828x over previous
//
#include <hip/hip_runtime.h>

#define B_     128
#define S_     256
#define MW_    21
#define VOCAB_ 100
#define EC_    50
#define EW_    256
#define KW_    5
#define T_     17              // MW - K + 1
#define NW_    (B_ * S_)       // 32768 words
#define GROWS  (VOCAB_ * KW_)  // 500
#define WPB    64              // words per block (R8: 64KB LDS -> 2 blocks/CU)
#define CCH    32              // channels per chunk (8 chunks, 1 K-slice each)
#define P1B    200             // prep part-1 blocks

typedef _Float16 f16x8 __attribute__((ext_vector_type(8)));
typedef float    f32x4 __attribute__((ext_vector_type(4)));

// ---------------- kernel 1: prep (unchanged from R1)
__global__ __launch_bounds__(256) void k_prep(const float* __restrict__ emb,
                                              const float* __restrict__ cw,
                                              const float* __restrict__ Wp,
                                              const float* __restrict__ Wg,
                                              _Float16* __restrict__ g,
                                              _Float16* __restrict__ wpf,
                                              _Float16* __restrict__ wgf) {
  const int bi = blockIdx.x;
  if (bi < P1B) {
    __shared__ float ls[64 * 250];          // one o-tile of cw, natural layout
    const int vp = bi >> 2, ot = bi & 3;
    const int o0 = ot * 64;
    const int tid = threadIdx.x;
    const float4* __restrict__ cw4 = (const float4*)cw + ot * 4000;  // tile base
#pragma unroll 4
    for (int idx4 = tid; idx4 < 4000; idx4 += 256)
      *(float4*)&ls[idx4 * 4] = cw4[idx4];
    __syncthreads();

    const int l = tid & 63, wv = tid >> 6;   // lane = o_local, wave = k (0..3)
#pragma unroll
    for (int vv = 0; vv < 2; ++vv) {
      const int v = vp * 2 + vv;
      const float* __restrict__ er = emb + v * EC_;   // uniform -> s_load
      float acc = 0.f;
#pragma unroll
      for (int i = 0; i < EC_; ++i)
        acc += er[i] * ls[l * 250 + i * KW_ + wv];
      g[(v * KW_ + wv) * EW_ + o0 + l] = (_Float16)acc;
      if (wv == 0) {                          // wave 0 also covers k = 4
        float a4 = 0.f;
#pragma unroll
        for (int i = 0; i < EC_; ++i)
          a4 += er[i] * ls[l * 250 + i * KW_ + 4];
        g[(v * KW_ + 4) * EW_ + o0 + l] = (_Float16)a4;
      }
    }
  } else {
    const int fl  = (bi - P1B) * 256 + threadIdx.x;  // 0..8191 lane-frags
    const int nt  = fl >> 9;
    const int rem = fl & 511;
    const int ks  = rem >> 6;
    const int l   = rem & 63;
    const int n   = nt * 16 + (l & 15);
    const int kc  = ks * 32 + (l >> 4) * 8;
    const int src = n * EW_ + kc;
    const float4 p0 = *(const float4*)&Wp[src], p1 = *(const float4*)&Wp[src + 4];
    const float4 q0 = *(const float4*)&Wg[src], q1 = *(const float4*)&Wg[src + 4];
    f16x8 hp = {(_Float16)p0.x, (_Float16)p0.y, (_Float16)p0.z, (_Float16)p0.w,
                (_Float16)p1.x, (_Float16)p1.y, (_Float16)p1.z, (_Float16)p1.w};
    f16x8 hg = {(_Float16)q0.x, (_Float16)q0.y, (_Float16)q0.z, (_Float16)q0.w,
                (_Float16)q1.x, (_Float16)q1.y, (_Float16)q1.z, (_Float16)q1.w};
    *(f16x8*)&wpf[fl * 8] = hp;
    *(f16x8*)&wgf[fl * 8] = hg;
  }
}

// ---------------- kernel 2: mega — R8: 2 BLOCKS/CU for cross-block overlap
// R7's intra-block role split failed (spill + halved gather parallelism).
// This round keeps per-task code IDENTICAL to the proven R0/R6 conv (85
// b128 reads/task, same sum/max order -> bitwise-identical y) but shrinks the
// block to 64 KB LDS so TWO blocks co-reside per CU: one block's phase B
// (MFMA + L2 B-stream + HBM writes) overlaps the other's port-bound gather.
//  - 256 thr (4 waves), WPB=64, 8 chunks x 32 channels (1 K-slice per chunk).
//    Per chunk: 64 words x 4 octets = 256 tasks = exactly 1 per thread.
//  - y_s placement lt = ((w+4*og)&15)|(og<<4): conflict-free on write and on
//    A-frag read by construction (each 16-lane phase covers 16 distinct 16B
//    slots); replaces the old XOR swizzle.
//  - acc (128 VGPR) live only in phase B; base[21]+pre[8] only in phase A ->
//    peak ~200 VGPR. LDS caps blocks/CU at 2, so the heuristic's wave target
//    is 8/CU = 2/SIMD -> 256-VGPR budget, no spill incentive (R5/R6 regime).
// g_s: plain stride-32 rows (64 B; rows stay 16B-aligned, linear staging).
__global__ __launch_bounds__(256, 2) void k_mega(const int* __restrict__ idx,
                                                 const _Float16* __restrict__ g,
                                                 const float* __restrict__ cb,
                                                 const _Float16* __restrict__ wpf,
                                                 const _Float16* __restrict__ wgf,
                                                 const float* __restrict__ bp,
                                                 const float* __restrict__ bg,
                                                 float* __restrict__ out) {
  __shared__ __align__(16) _Float16 lds[16384 + GROWS * CCH];
  _Float16* y_s = lds;            // [4mt][8ks][64 lt][8j] = 16384 halves (32 KB)
  _Float16* g_s = lds + 16384;    // [500][32] = 16000 halves (32 KB)

  const int tid  = threadIdx.x;
  const int wave = tid >> 6, lane = tid & 63;
  const int m0 = blockIdx.x * WPB;
  const int w  = tid >> 2;                   // word 0..63 (one per 4 threads)
  const int og = tid & 3;                    // channel-octet within 32-ch chunk

  // initial stage: chunk 0  (2000 b128 lane-writes, linear dest = c*8 halves)
#pragma unroll
  for (int i = 0; i < 8; ++i) {
    const int c = tid + i * 256;
    if (c < GROWS * 4) {
      const int row = c >> 2, cc = c & 3;
      *(f16x8*)&g_s[row * CCH + cc * 8] = *(const f16x8*)&g[row * EW_ + cc * 8];
    }
  }
  __syncthreads();

  // per-word constants, chunk-invariant
  const int* __restrict__ ipr = idx + (m0 + w) * MW_;
  int base[MW_];
#pragma unroll
  for (int c = 0; c < MW_; ++c)
    base[c] = ipr[c] * (KW_ * CCH) + og * 8;
  const int mt_a = w >> 4;
  const int lt   = (((w & 15) + 4 * og) & 15) | (og << 4);  // conflict-free slot

  f16x8 pre[8];
#pragma unroll
  for (int chunk = 0; chunk < 8; ++chunk) {
    const int oc0 = chunk * CCH;
    // issue next chunk's staging loads into registers
    if (chunk < 7) {
#pragma unroll
      for (int i = 0; i < 8; ++i) {
        const int c = tid + i * 256;
        if (c < GROWS * 4) {
          const int row = c >> 2, cc = c & 3;
          pre[i] = *(const f16x8*)&g[row * EW_ + oc0 + CCH + cc * 8];
        }
      }
    }

    f16x8 bias;
#pragma unroll
    for (int j = 0; j < 8; ++j) bias[j] = (_Float16)cb[oc0 + og * 8 + j];

    const _Float16 NEG = (_Float16)(-60000.0f);
    f16x8 mx = {NEG, NEG, NEG, NEG, NEG, NEG, NEG, NEG};
#pragma unroll
    for (int t = 0; t < T_; ++t) {
      f16x8 s = *(const f16x8*)&g_s[base[t]];              // k = 0
#pragma unroll
      for (int k = 1; k < KW_; ++k)
        s += *(const f16x8*)&g_s[base[t + k] + k * CCH];   // v_pk_add_f16
      mx = __builtin_elementwise_max(mx, s);               // v_pk_max_f16
    }
    // relu(bias + max_t s) == max_t relu(bias + s)
    const f16x8 zero8 = {0, 0, 0, 0, 0, 0, 0, 0};
    mx = __builtin_elementwise_max(mx + bias, zero8);

    *(f16x8*)&y_s[((mt_a * 8 + chunk) * 64 + lt) * 8] = mx;

    __syncthreads();  // gather(c)+y-writes complete; g_s free
    if (chunk < 7) {
#pragma unroll
      for (int i = 0; i < 8; ++i) {
        const int c = tid + i * 256;
        if (c < GROWS * 4) {
          const int row = c >> 2, cc = c & 3;
          *(f16x8*)&g_s[row * CCH + cc * 8] = pre[i];
        }
      }
      __syncthreads();
    }
  }

  // ======== phase B: dual GEMM + highway — wave = n-quarter, all 4 m-tiles ====
  const int nq = wave;                       // 0..3
  const int quad = lane >> 4, r16 = lane & 15;
  const int koct = lane >> 4;
  const int ltr = (((lane & 15) + 4 * koct) & 15) | (koct << 4);

  const f32x4 zero = {0.f, 0.f, 0.f, 0.f};
  f32x4 accp[4][4], accg[4][4];
#pragma unroll
  for (int mi = 0; mi < 4; ++mi)
#pragma unroll
    for (int nf = 0; nf < 4; ++nf) { accp[mi][nf] = zero; accg[mi][nf] = zero; }

#pragma unroll
  for (int ks = 0; ks < 8; ++ks) {
    f16x8 a[4];
#pragma unroll
    for (int mi = 0; mi < 4; ++mi)
      a[mi] = *(const f16x8*)&y_s[((mi * 8 + ks) * 64 + ltr) * 8];
#pragma unroll
    for (int nf = 0; nf < 4; ++nf) {
      const int nt = nq * 4 + nf;
      const int off = ((nt * 8 + ks) * 64 + lane) * 8;
      const f16x8 bpv = *(const f16x8*)&wpf[off];
      const f16x8 bgv = *(const f16x8*)&wgf[off];
#pragma unroll
      for (int mi = 0; mi < 4; ++mi) {
        accp[mi][nf] = __builtin_amdgcn_mfma_f32_16x16x32_f16(a[mi], bpv, accp[mi][nf], 0, 0, 0);
        accg[mi][nf] = __builtin_amdgcn_mfma_f32_16x16x32_f16(a[mi], bgv, accg[mi][nf], 0, 0, 0);
      }
    }
  }

  // epilogue
#pragma unroll
  for (int mi = 0; mi < 4; ++mi) {
#pragma unroll
    for (int nf = 0; nf < 4; ++nf) {
      const int n = nq * 64 + nf * 16 + r16;
      const float bpn = bp[n];
      const float bgn = bg[n];
      const int ks_e = n >> 5;
      const int og_e = (n >> 3) & 3;
      const int je = n & 7;
#pragma unroll
      for (int reg = 0; reg < 4; ++reg) {
        const int m = mi * 16 + quad * 4 + reg;
        const int lt_e = (((m & 15) + 4 * og_e) & 15) | (og_e << 4);
        float p = fmaxf(accp[mi][nf][reg] + bpn, 0.f);
        const float gz = accg[mi][nf][reg] + bgn;
        const float gate = 1.f / (1.f + __expf(-gz));
        const float yv = (float)y_s[((mi * 8 + ks_e) * 64 + lt_e) * 8 + je];
        out[(m0 + m) * EW_ + n] = gate * p + (1.f - gate) * yv;
      }
    }
  }
}

extern "C" void kernel_launch(void* const* d_in, const int* in_sizes, int n_in,
                              void* d_out, int out_size, void* d_ws, size_t ws_size,
                              hipStream_t stream) {
  (void)in_sizes; (void)n_in; (void)out_size; (void)ws_size;
  const int*   idx = (const int*)d_in[0];
  const float* emb = (const float*)d_in[1];
  const float* cw  = (const float*)d_in[2];
  const float* cb  = (const float*)d_in[3];
  const float* wp  = (const float*)d_in[4];
  const float* bpp = (const float*)d_in[5];
  const float* wgt = (const float*)d_in[6];
  const float* bgg = (const float*)d_in[7];
  float* out = (float*)d_out;
  _Float16* g_ws = (_Float16*)d_ws;            // 500*256 fp16
  _Float16* wp_f = g_ws + GROWS * EW_;         // 65536 halves, frag order
  _Float16* wg_f = wp_f + EW_ * EW_;           // 65536 halves, frag order

  k_prep<<<P1B + 32, 256, 0, stream>>>(emb, cw, wp, wgt, g_ws, wp_f, wg_f);
  k_mega<<<NW_ / WPB, 256, 0, stream>>>(idx, g_ws, cb, wp_f, wg_f, bpp, bgg, out);
}

// Round 9
// 120.381 us; speedup vs baseline: 1.2905x; 1.0060x over previous
//
#include <hip/hip_runtime.h>

#define B_     128
#define S_     256
#define MW_    21
#define VOCAB_ 100
#define EC_    50
#define EW_    256
#define KW_    5
#define T_     17              // MW - K + 1
#define NW_    (B_ * S_)       // 32768 words
#define GROWS  (VOCAB_ * KW_)  // 500
#define WPB    128             // words per mega block
#define P1B    200             // prep part-1 blocks: 50 v-pairs x 4 o-tiles

typedef _Float16 f16x8 __attribute__((ext_vector_type(8)));
typedef float    f32x4 __attribute__((ext_vector_type(4)));

// ---------------- kernel 1: prep (unchanged from R1)
__global__ __launch_bounds__(256) void k_prep(const float* __restrict__ emb,
                                              const float* __restrict__ cw,
                                              const float* __restrict__ Wp,
                                              const float* __restrict__ Wg,
                                              _Float16* __restrict__ g,
                                              _Float16* __restrict__ wpf,
                                              _Float16* __restrict__ wgf) {
  const int bi = blockIdx.x;
  if (bi < P1B) {
    __shared__ float ls[64 * 250];          // one o-tile of cw, natural layout
    const int vp = bi >> 2, ot = bi & 3;
    const int o0 = ot * 64;
    const int tid = threadIdx.x;
    const float4* __restrict__ cw4 = (const float4*)cw + ot * 4000;  // tile base
#pragma unroll 4
    for (int idx4 = tid; idx4 < 4000; idx4 += 256)
      *(float4*)&ls[idx4 * 4] = cw4[idx4];
    __syncthreads();

    const int l = tid & 63, wv = tid >> 6;   // lane = o_local, wave = k (0..3)
#pragma unroll
    for (int vv = 0; vv < 2; ++vv) {
      const int v = vp * 2 + vv;
      const float* __restrict__ er = emb + v * EC_;   // uniform -> s_load
      float acc = 0.f;
#pragma unroll
      for (int i = 0; i < EC_; ++i)
        acc += er[i] * ls[l * 250 + i * KW_ + wv];
      g[(v * KW_ + wv) * EW_ + o0 + l] = (_Float16)acc;
      if (wv == 0) {                          // wave 0 also covers k = 4
        float a4 = 0.f;
#pragma unroll
        for (int i = 0; i < EC_; ++i)
          a4 += er[i] * ls[l * 250 + i * KW_ + 4];
        g[(v * KW_ + 4) * EW_ + o0 + l] = (_Float16)a4;
      }
    }
  } else {
    const int fl  = (bi - P1B) * 256 + threadIdx.x;  // 0..8191 lane-frags
    const int nt  = fl >> 9;
    const int rem = fl & 511;
    const int ks  = rem >> 6;
    const int l   = rem & 63;
    const int n   = nt * 16 + (l & 15);
    const int kc  = ks * 32 + (l >> 4) * 8;
    const int src = n * EW_ + kc;
    const float4 p0 = *(const float4*)&Wp[src], p1 = *(const float4*)&Wp[src + 4];
    const float4 q0 = *(const float4*)&Wg[src], q1 = *(const float4*)&Wg[src + 4];
    f16x8 hp = {(_Float16)p0.x, (_Float16)p0.y, (_Float16)p0.z, (_Float16)p0.w,
                (_Float16)p1.x, (_Float16)p1.y, (_Float16)p1.z, (_Float16)p1.w};
    f16x8 hg = {(_Float16)q0.x, (_Float16)q0.y, (_Float16)q0.z, (_Float16)q0.w,
                (_Float16)q1.x, (_Float16)q1.y, (_Float16)q1.z, (_Float16)q1.w};
    *(f16x8*)&wpf[fl * 8] = hp;
    *(f16x8*)&wgf[fl * 8] = hg;
  }
}

// ---------------- kernel 2: mega — conv+relu+maxpool (A) + dual-GEMM highway (B)
// R9: phase A = bit-exact R6/R0 (at its floor: 5440 ds_read_b128/CU x 12cyc
//   ~27us + inherent 4.12M conflict cyc ~7us; 3 layout changes all made it
//   worse; 4 overlap mechanisms all null). Phase B REGISTER-PIPELINED:
//   R6's acc used 128 regs (116 VGPR + ~128 AGPR ~ 244/256 budget) leaving
//   nothing to pipeline the 64 B-frag L2 loads (~200cy each) -> MFMA pipe busy
//   only ~3.3us of ~12us. Split phase B into TWO n-pair passes (nf = np*2+{0,1}):
//   acc = 64 regs/pass, freed regs hold a double-buffered next-ks B-frag set
//   (4 frags in flight while MFMA'ing current ks). B bytes unchanged (n-range
//   partitioned, no re-read); ks ascending 0..7 per column -> bitwise-identical
//   numerics. a[] re-read per pass (+32 ds_read/wave, negligible).
__global__ __launch_bounds__(512, 2) void k_mega(const int* __restrict__ idx,
                                                 const _Float16* __restrict__ g,
                                                 const float* __restrict__ cb,
                                                 const _Float16* __restrict__ wpf,
                                                 const _Float16* __restrict__ wgf,
                                                 const float* __restrict__ bp,
                                                 const float* __restrict__ bg,
                                                 float* __restrict__ out) {
  __shared__ __align__(16) _Float16 lds[32768 + GROWS * 64];
  _Float16* y_s = lds;            // 32768 halves: (frag*64 + (lane_t^og)) * 8 + j
  _Float16* g_s = lds + 32768;    // [500][64]

  const int tid  = threadIdx.x;
  const int wave = tid >> 6, lane = tid & 63;
  const int m0 = blockIdx.x * WPB;
  const int wq = lane >> 3, og = lane & 7;   // 8 words x 8 channel-octets per wave

  // initial stage: chunk 0
#pragma unroll
  for (int i = 0; i < 8; ++i) {
    const int c = tid + i * 512;
    if (c < GROWS * 8) {
      const int row = c >> 3, cc = c & 7;
      *(f16x8*)&g_s[row * 64 + cc * 8] = *(const f16x8*)&g[row * EW_ + cc * 8];
    }
  }
  __syncthreads();

  f16x8 pre[8];
#pragma unroll
  for (int chunk = 0; chunk < 4; ++chunk) {
    const int oc0 = chunk * 64;
    // issue next chunk's loads into registers (waited only at the ds_write below)
    if (chunk < 3) {
#pragma unroll
      for (int i = 0; i < 8; ++i) {
        const int c = tid + i * 512;
        if (c < GROWS * 8) {
          const int row = c >> 3, cc = c & 7;
          pre[i] = *(const f16x8*)&g[row * EW_ + oc0 + 64 + cc * 8];
        }
      }
    }

    f16x8 bias;
#pragma unroll
    for (int j = 0; j < 8; ++j) bias[j] = (_Float16)cb[oc0 + og * 8 + j];

    const int ks_w    = chunk * 2 + (og >> 2);
    const int lane_hi = (og & 3) << 4;

#pragma unroll
    for (int it = 0; it < 2; ++it) {
      const int wl = it * 64 + wave * 8 + wq;
      const int* __restrict__ ip = idx + (m0 + wl) * MW_;
      int base[MW_];
#pragma unroll
      for (int c = 0; c < MW_; ++c)
        base[c] = ip[c] * (KW_ * 64) + og * 8;

      const _Float16 NEG = (_Float16)(-60000.0f);
      f16x8 mx = {NEG, NEG, NEG, NEG, NEG, NEG, NEG, NEG};
#pragma unroll
      for (int t = 0; t < T_; ++t) {
        f16x8 s = *(const f16x8*)&g_s[base[t]];              // k = 0
#pragma unroll
        for (int k = 1; k < KW_; ++k)
          s += *(const f16x8*)&g_s[base[t + k] + k * 64];    // v_pk_add_f16
        mx = __builtin_elementwise_max(mx, s);               // v_pk_max_f16
      }
      // relu(bias + max_t s) == max_t relu(bias + s)
      const f16x8 zero8 = {0, 0, 0, 0, 0, 0, 0, 0};
      mx = __builtin_elementwise_max(mx + bias, zero8);

      const int mt = wl >> 4;
      const int lt = ((wl & 15) | lane_hi) ^ og;             // swizzled granule low-6
      *(f16x8*)&y_s[((mt * 8 + ks_w) * 64 + lt) * 8] = mx;
    }
    __syncthreads();  // gather(c)+y-writes complete; g_s free
    if (chunk < 3) {
#pragma unroll
      for (int i = 0; i < 8; ++i) {
        const int c = tid + i * 512;
        if (c < GROWS * 8) {
          const int row = c >> 3, cc = c & 7;
          *(f16x8*)&g_s[row * 64 + cc * 8] = pre[i];
        }
      }
      __syncthreads();
    }
  }

  // ======== phase B: dual GEMM + highway — two n-pair passes, B double-buffered
  const int mtp2 = wave >> 2, nq = wave & 3;   // 2 m-groups x 4 n-quarters
  const int quad = lane >> 4, r16 = lane & 15;
  const f32x4 zero = {0.f, 0.f, 0.f, 0.f};

#pragma unroll
  for (int np = 0; np < 2; ++np) {             // n-pair: nf = np*2 + {0,1}
    f32x4 accp[4][2], accg[4][2];
#pragma unroll
    for (int mi = 0; mi < 4; ++mi)
#pragma unroll
      for (int nf2 = 0; nf2 < 2; ++nf2) { accp[mi][nf2] = zero; accg[mi][nf2] = zero; }

    f16x8 bpv[2][2], bgv[2][2];                // [buf][nf2], buf = ks&1 (static)
#pragma unroll
    for (int nf2 = 0; nf2 < 2; ++nf2) {
      const int nt = nq * 4 + np * 2 + nf2;
      bpv[0][nf2] = *(const f16x8*)&wpf[((nt * 8 + 0) * 64 + lane) * 8];
      bgv[0][nf2] = *(const f16x8*)&wgf[((nt * 8 + 0) * 64 + lane) * 8];
    }

#pragma unroll
    for (int ks = 0; ks < 8; ++ks) {
      const int cur = ks & 1, nxt = cur ^ 1;   // static under full unroll
      if (ks < 7) {
#pragma unroll
        for (int nf2 = 0; nf2 < 2; ++nf2) {
          const int nt = nq * 4 + np * 2 + nf2;
          bpv[nxt][nf2] = *(const f16x8*)&wpf[((nt * 8 + ks + 1) * 64 + lane) * 8];
          bgv[nxt][nf2] = *(const f16x8*)&wgf[((nt * 8 + ks + 1) * 64 + lane) * 8];
        }
      }
      const int key = ((ks & 1) << 2) | quad;  // == writer og
      f16x8 a[4];
#pragma unroll
      for (int mi = 0; mi < 4; ++mi)
        a[mi] = *(const f16x8*)&y_s[(((mtp2 * 4 + mi) * 8 + ks) * 64 + (lane ^ key)) * 8];
#pragma unroll
      for (int nf2 = 0; nf2 < 2; ++nf2)
#pragma unroll
        for (int mi = 0; mi < 4; ++mi) {
          accp[mi][nf2] = __builtin_amdgcn_mfma_f32_16x16x32_f16(a[mi], bpv[cur][nf2], accp[mi][nf2], 0, 0, 0);
          accg[mi][nf2] = __builtin_amdgcn_mfma_f32_16x16x32_f16(a[mi], bgv[cur][nf2], accg[mi][nf2], 0, 0, 0);
        }
    }

    // epilogue for this n-pair
#pragma unroll
    for (int mi = 0; mi < 4; ++mi) {
      const int mt = mtp2 * 4 + mi;
#pragma unroll
      for (int nf2 = 0; nf2 < 2; ++nf2) {
        const int n = nq * 64 + (np * 2 + nf2) * 16 + r16;
        const float bpn = bp[n];
        const float bgn = bg[n];
        const int ks_e = n >> 5;
        const int lane_e = ((n >> 3) & 3) << 4;
        const int og_e = (n >> 3) & 7;
        const int je = n & 7;
#pragma unroll
        for (int reg = 0; reg < 4; ++reg) {
          const int m = mt * 16 + quad * 4 + reg;
          float p = fmaxf(accp[mi][nf2][reg] + bpn, 0.f);
          const float gz = accg[mi][nf2][reg] + bgn;
          const float gate = 1.f / (1.f + __expf(-gz));
          const float yv =
              (float)y_s[((mt * 8 + ks_e) * 64 + (((m & 15) | lane_e) ^ og_e)) * 8 + je];
          out[(m0 + m) * EW_ + n] = gate * p + (1.f - gate) * yv;
        }
      }
    }
  }
}

extern "C" void kernel_launch(void* const* d_in, const int* in_sizes, int n_in,
                              void* d_out, int out_size, void* d_ws, size_t ws_size,
                              hipStream_t stream) {
  (void)in_sizes; (void)n_in; (void)out_size; (void)ws_size;
  const int*   idx = (const int*)d_in[0];
  const float* emb = (const float*)d_in[1];
  const float* cw  = (const float*)d_in[2];
  const float* cb  = (const float*)d_in[3];
  const float* wp  = (const float*)d_in[4];
  const float* bpp = (const float*)d_in[5];
  const float* wgt = (const float*)d_in[6];
  const float* bgg = (const float*)d_in[7];
  float* out = (float*)d_out;
  _Float16* g_ws = (_Float16*)d_ws;            // 500*256 fp16
  _Float16* wp_f = g_ws + GROWS * EW_;         // 65536 halves, frag order
  _Float16* wg_f = wp_f + EW_ * EW_;           // 65536 halves, frag order

  k_prep<<<P1B + 32, 256, 0, stream>>>(emb, cw, wp, wgt, g_ws, wp_f, wg_f);
  k_mega<<<NW_ / WPB, 512, 0, stream>>>(idx, g_ws, cb, wp_f, wg_f, bpp, bgg, out);
}

// Round 10
// 119.265 us; speedup vs baseline: 1.3026x; 1.0094x over previous
//
#include <hip/hip_runtime.h>

#define B_     128
#define S_     256
#define MW_    21
#define VOCAB_ 100
#define EC_    50
#define EW_    256
#define KW_    5
#define T_     17              // MW - K + 1
#define NW_    (B_ * S_)       // 32768 words
#define GROWS  (VOCAB_ * KW_)  // 500
#define WPB    128             // words per mega block
#define P1B    200             // prep part-1 blocks: 50 v-pairs x 4 o-tiles

typedef _Float16 f16x8 __attribute__((ext_vector_type(8)));
typedef float    f32x4 __attribute__((ext_vector_type(4)));

// ---------------- kernel 1: prep (unchanged from R1)
__global__ __launch_bounds__(256) void k_prep(const float* __restrict__ emb,
                                              const float* __restrict__ cw,
                                              const float* __restrict__ Wp,
                                              const float* __restrict__ Wg,
                                              _Float16* __restrict__ g,
                                              _Float16* __restrict__ wpf,
                                              _Float16* __restrict__ wgf) {
  const int bi = blockIdx.x;
  if (bi < P1B) {
    __shared__ float ls[64 * 250];          // one o-tile of cw, natural layout
    const int vp = bi >> 2, ot = bi & 3;
    const int o0 = ot * 64;
    const int tid = threadIdx.x;
    const float4* __restrict__ cw4 = (const float4*)cw + ot * 4000;  // tile base
#pragma unroll 4
    for (int idx4 = tid; idx4 < 4000; idx4 += 256)
      *(float4*)&ls[idx4 * 4] = cw4[idx4];
    __syncthreads();

    const int l = tid & 63, wv = tid >> 6;   // lane = o_local, wave = k (0..3)
#pragma unroll
    for (int vv = 0; vv < 2; ++vv) {
      const int v = vp * 2 + vv;
      const float* __restrict__ er = emb + v * EC_;   // uniform -> s_load
      float acc = 0.f;
#pragma unroll
      for (int i = 0; i < EC_; ++i)
        acc += er[i] * ls[l * 250 + i * KW_ + wv];
      g[(v * KW_ + wv) * EW_ + o0 + l] = (_Float16)acc;
      if (wv == 0) {                          // wave 0 also covers k = 4
        float a4 = 0.f;
#pragma unroll
        for (int i = 0; i < EC_; ++i)
          a4 += er[i] * ls[l * 250 + i * KW_ + 4];
        g[(v * KW_ + 4) * EW_ + o0 + l] = (_Float16)a4;
      }
    }
  } else {
    const int fl  = (bi - P1B) * 256 + threadIdx.x;  // 0..8191 lane-frags
    const int nt  = fl >> 9;
    const int rem = fl & 511;
    const int ks  = rem >> 6;
    const int l   = rem & 63;
    const int n   = nt * 16 + (l & 15);
    const int kc  = ks * 32 + (l >> 4) * 8;
    const int src = n * EW_ + kc;
    const float4 p0 = *(const float4*)&Wp[src], p1 = *(const float4*)&Wp[src + 4];
    const float4 q0 = *(const float4*)&Wg[src], q1 = *(const float4*)&Wg[src + 4];
    f16x8 hp = {(_Float16)p0.x, (_Float16)p0.y, (_Float16)p0.z, (_Float16)p0.w,
                (_Float16)p1.x, (_Float16)p1.y, (_Float16)p1.z, (_Float16)p1.w};
    f16x8 hg = {(_Float16)q0.x, (_Float16)q0.y, (_Float16)q0.z, (_Float16)q0.w,
                (_Float16)q1.x, (_Float16)q1.y, (_Float16)q1.z, (_Float16)q1.w};
    *(f16x8*)&wpf[fl * 8] = hp;
    *(f16x8*)&wgf[fl * 8] = hg;
  }
}

// ---------------- kernel 2: mega — conv+relu+maxpool (A) + dual-GEMM highway (B)
// R10: phase A bit-exact (at its LDS-port roofline: 27us issue + 7us structural
//   b128 overhead — the 4,122,024 "conflict" count is deterministic and data-
//   independent, i.e. NOT layout-fixable; 3 layout attempts all regressed).
// Phase B: R9's distance-1 B-pipelining won 1.9us but covers only ~150cy of the
//   ~200cy L2 latency. This round: (a) B-fragments 3-deep rotation (distance-2,
//   ~300cy coverage); (b) A-fragment LDS reads (~120cy latency) double-buffered
//   distance-1. All buffer indices compile-time (ks%3, ks&1 under full unroll).
//   ks stays ascending 0..7 per accumulator -> bitwise-identical numerics.
//   Regs: acc 64 + B 48 + a 32 + addr ~25 ≈ 170 < 256 @ 2 waves/SIMD.
__global__ __launch_bounds__(512, 2) void k_mega(const int* __restrict__ idx,
                                                 const _Float16* __restrict__ g,
                                                 const float* __restrict__ cb,
                                                 const _Float16* __restrict__ wpf,
                                                 const _Float16* __restrict__ wgf,
                                                 const float* __restrict__ bp,
                                                 const float* __restrict__ bg,
                                                 float* __restrict__ out) {
  __shared__ __align__(16) _Float16 lds[32768 + GROWS * 64];
  _Float16* y_s = lds;            // 32768 halves: (frag*64 + (lane_t^og)) * 8 + j
  _Float16* g_s = lds + 32768;    // [500][64]

  const int tid  = threadIdx.x;
  const int wave = tid >> 6, lane = tid & 63;
  const int m0 = blockIdx.x * WPB;
  const int wq = lane >> 3, og = lane & 7;   // 8 words x 8 channel-octets per wave

  // initial stage: chunk 0
#pragma unroll
  for (int i = 0; i < 8; ++i) {
    const int c = tid + i * 512;
    if (c < GROWS * 8) {
      const int row = c >> 3, cc = c & 7;
      *(f16x8*)&g_s[row * 64 + cc * 8] = *(const f16x8*)&g[row * EW_ + cc * 8];
    }
  }
  __syncthreads();

  f16x8 pre[8];
#pragma unroll
  for (int chunk = 0; chunk < 4; ++chunk) {
    const int oc0 = chunk * 64;
    // issue next chunk's loads into registers (waited only at the ds_write below)
    if (chunk < 3) {
#pragma unroll
      for (int i = 0; i < 8; ++i) {
        const int c = tid + i * 512;
        if (c < GROWS * 8) {
          const int row = c >> 3, cc = c & 7;
          pre[i] = *(const f16x8*)&g[row * EW_ + oc0 + 64 + cc * 8];
        }
      }
    }

    f16x8 bias;
#pragma unroll
    for (int j = 0; j < 8; ++j) bias[j] = (_Float16)cb[oc0 + og * 8 + j];

    const int ks_w    = chunk * 2 + (og >> 2);
    const int lane_hi = (og & 3) << 4;

#pragma unroll
    for (int it = 0; it < 2; ++it) {
      const int wl = it * 64 + wave * 8 + wq;
      const int* __restrict__ ip = idx + (m0 + wl) * MW_;
      int base[MW_];
#pragma unroll
      for (int c = 0; c < MW_; ++c)
        base[c] = ip[c] * (KW_ * 64) + og * 8;

      const _Float16 NEG = (_Float16)(-60000.0f);
      f16x8 mx = {NEG, NEG, NEG, NEG, NEG, NEG, NEG, NEG};
#pragma unroll
      for (int t = 0; t < T_; ++t) {
        f16x8 s = *(const f16x8*)&g_s[base[t]];              // k = 0
#pragma unroll
        for (int k = 1; k < KW_; ++k)
          s += *(const f16x8*)&g_s[base[t + k] + k * 64];    // v_pk_add_f16
        mx = __builtin_elementwise_max(mx, s);               // v_pk_max_f16
      }
      // relu(bias + max_t s) == max_t relu(bias + s)
      const f16x8 zero8 = {0, 0, 0, 0, 0, 0, 0, 0};
      mx = __builtin_elementwise_max(mx + bias, zero8);

      const int mt = wl >> 4;
      const int lt = ((wl & 15) | lane_hi) ^ og;             // swizzled granule low-6
      *(f16x8*)&y_s[((mt * 8 + ks_w) * 64 + lt) * 8] = mx;
    }
    __syncthreads();  // gather(c)+y-writes complete; g_s free
    if (chunk < 3) {
#pragma unroll
      for (int i = 0; i < 8; ++i) {
        const int c = tid + i * 512;
        if (c < GROWS * 8) {
          const int row = c >> 3, cc = c & 7;
          *(f16x8*)&g_s[row * 64 + cc * 8] = pre[i];
        }
      }
      __syncthreads();
    }
  }

  // ======== phase B: dual GEMM + highway — 2 n-pair passes, B 3-deep, a 2-deep
  const int mtp2 = wave >> 2, nq = wave & 3;   // 2 m-groups x 4 n-quarters
  const int quad = lane >> 4, r16 = lane & 15;
  const f32x4 zero = {0.f, 0.f, 0.f, 0.f};

#pragma unroll
  for (int np = 0; np < 2; ++np) {             // n-pair: nf = np*2 + {0,1}
    f32x4 accp[4][2], accg[4][2];
#pragma unroll
    for (int mi = 0; mi < 4; ++mi)
#pragma unroll
      for (int nf2 = 0; nf2 < 2; ++nf2) { accp[mi][nf2] = zero; accg[mi][nf2] = zero; }

    const int ntb = nq * 4 + np * 2;
    f16x8 bpv[3][2], bgv[3][2];                // 3-deep rotation, idx = ks % 3
    f16x8 av[2][4];                            // 2-deep a-frags, idx = ks & 1

    // prologue: B for ks=0,1; a for ks=0
#pragma unroll
    for (int pk = 0; pk < 2; ++pk)
#pragma unroll
      for (int nf2 = 0; nf2 < 2; ++nf2) {
        const int nt = ntb + nf2;
        bpv[pk][nf2] = *(const f16x8*)&wpf[((nt * 8 + pk) * 64 + lane) * 8];
        bgv[pk][nf2] = *(const f16x8*)&wgf[((nt * 8 + pk) * 64 + lane) * 8];
      }
#pragma unroll
    for (int mi = 0; mi < 4; ++mi)
      av[0][mi] = *(const f16x8*)&y_s[(((mtp2 * 4 + mi) * 8 + 0) * 64 + (lane ^ quad)) * 8];

#pragma unroll
    for (int ks = 0; ks < 8; ++ks) {
      const int cur = ks % 3;                  // compile-time under full unroll
      if (ks < 6) {
        const int nx = (ks + 2) % 3;
#pragma unroll
        for (int nf2 = 0; nf2 < 2; ++nf2) {
          const int nt = ntb + nf2;
          bpv[nx][nf2] = *(const f16x8*)&wpf[((nt * 8 + ks + 2) * 64 + lane) * 8];
          bgv[nx][nf2] = *(const f16x8*)&wgf[((nt * 8 + ks + 2) * 64 + lane) * 8];
        }
      }
      if (ks < 7) {
        const int an  = (ks + 1) & 1;
        const int key = (((ks + 1) & 1) << 2) | quad;        // == writer og
#pragma unroll
        for (int mi = 0; mi < 4; ++mi)
          av[an][mi] =
              *(const f16x8*)&y_s[(((mtp2 * 4 + mi) * 8 + ks + 1) * 64 + (lane ^ key)) * 8];
      }
      const int ac = ks & 1;
#pragma unroll
      for (int nf2 = 0; nf2 < 2; ++nf2)
#pragma unroll
        for (int mi = 0; mi < 4; ++mi) {
          accp[mi][nf2] = __builtin_amdgcn_mfma_f32_16x16x32_f16(av[ac][mi], bpv[cur][nf2], accp[mi][nf2], 0, 0, 0);
          accg[mi][nf2] = __builtin_amdgcn_mfma_f32_16x16x32_f16(av[ac][mi], bgv[cur][nf2], accg[mi][nf2], 0, 0, 0);
        }
    }

    // epilogue for this n-pair
#pragma unroll
    for (int mi = 0; mi < 4; ++mi) {
      const int mt = mtp2 * 4 + mi;
#pragma unroll
      for (int nf2 = 0; nf2 < 2; ++nf2) {
        const int n = nq * 64 + (np * 2 + nf2) * 16 + r16;
        const float bpn = bp[n];
        const float bgn = bg[n];
        const int ks_e = n >> 5;
        const int lane_e = ((n >> 3) & 3) << 4;
        const int og_e = (n >> 3) & 7;
        const int je = n & 7;
#pragma unroll
        for (int reg = 0; reg < 4; ++reg) {
          const int m = mt * 16 + quad * 4 + reg;
          float p = fmaxf(accp[mi][nf2][reg] + bpn, 0.f);
          const float gz = accg[mi][nf2][reg] + bgn;
          const float gate = 1.f / (1.f + __expf(-gz));
          const float yv =
              (float)y_s[((mt * 8 + ks_e) * 64 + (((m & 15) | lane_e) ^ og_e)) * 8 + je];
          out[(m0 + m) * EW_ + n] = gate * p + (1.f - gate) * yv;
        }
      }
    }
  }
}

extern "C" void kernel_launch(void* const* d_in, const int* in_sizes, int n_in,
                              void* d_out, int out_size, void* d_ws, size_t ws_size,
                              hipStream_t stream) {
  (void)in_sizes; (void)n_in; (void)out_size; (void)ws_size;
  const int*   idx = (const int*)d_in[0];
  const float* emb = (const float*)d_in[1];
  const float* cw  = (const float*)d_in[2];
  const float* cb  = (const float*)d_in[3];
  const float* wp  = (const float*)d_in[4];
  const float* bpp = (const float*)d_in[5];
  const float* wgt = (const float*)d_in[6];
  const float* bgg = (const float*)d_in[7];
  float* out = (float*)d_out;
  _Float16* g_ws = (_Float16*)d_ws;            // 500*256 fp16
  _Float16* wp_f = g_ws + GROWS * EW_;         // 65536 halves, frag order
  _Float16* wg_f = wp_f + EW_ * EW_;           // 65536 halves, frag order

  k_prep<<<P1B + 32, 256, 0, stream>>>(emb, cw, wp, wgt, g_ws, wp_f, wg_f);
  k_mega<<<NW_ / WPB, 512, 0, stream>>>(idx, g_ws, cb, wp_f, wg_f, bpp, bgg, out);
}